// Round 1
// baseline (167.367 us; speedup 1.0000x reference)
//
#include <hip/hip_runtime.h>
#include <hip/hip_bf16.h>

namespace {
constexpr int N_ = 4, H_ = 512, W_ = 512, K_ = 4;
constexpr int F_ = 200000;
constexpr float SIGMA_ = 1e-4f;
constexpr float GAMMA_ = 1e-4f;
constexpr float EPS_   = 1e-10f;
constexpr float ZNEAR_ = 1.0f, ZFAR_ = 100.0f;

typedef float        f32x4 __attribute__((ext_vector_type(4), aligned(4)));
typedef int          i32x4 __attribute__((ext_vector_type(4), aligned(4)));
typedef float        f32x3 __attribute__((ext_vector_type(3), aligned(4)));
typedef unsigned int u32x4 __attribute__((ext_vector_type(4), aligned(16)));
} // namespace

// R11: gather-early restructure. The 8 table-row gathers previously sat behind
// the full dists/zbuf HBM wait + sigmoid/exp/zmax VALU chain (address was
// (wn!=0 ? fidx : 0)). But ANY row with fidx>=0 is safe to read (every 16B bit
// pattern decodes to a finite vector: norm^2 > 0 always), and w==0 kills the
// contribution exactly. So the only required guard is max(fidx,0), which
// depends ONLY on ptf -> issue all 8 gathers immediately after the ptf load,
// overlapping them with the dists/zbuf/bary streaming loads and the weight
// VALU chain. Also fold w*b*inv into a single per-normal scale (defers the
// unit-ize muls into the blend; association delta << oct16 quantization).

__device__ __forceinline__ unsigned int oct_encode(float x, float y, float z) {
    const float inv = 1.0f / (fabsf(x) + fabsf(y) + fabsf(z)); // unit input
    const float px = x * inv, py = y * inv, pz = z * inv;
    // Standard octahedral wrap for the z<0 hemisphere: (1-|p.yx|)*sign(p.xy)
    const float wx = (1.0f - fabsf(py)) * copysignf(1.0f, px);
    const float wy = (1.0f - fabsf(px)) * copysignf(1.0f, py);
    const bool neg = pz < 0.0f;
    const float ex = neg ? wx : px;
    const float ey = neg ? wy : py;
    const int ix = (int)rintf(ex * 32767.0f);
    const int iy = (int)rintf(ey * 32767.0f);
    return ((unsigned int)ix & 0xffffu) | (((unsigned int)iy & 0xffffu) << 16);
}

// Raw decode: unnormalized vector + reciprocal norm (normalization is folded
// into the blend scale by the caller).
__device__ __forceinline__ void oct_decode_raw(unsigned int e,
                                               float& x, float& y, float& z,
                                               float& inv) {
    const float fx = (float)(short)(unsigned short)(e & 0xffffu) * (1.0f / 32767.0f);
    const float fy = (float)(short)(unsigned short)(e >> 16)     * (1.0f / 32767.0f);
    z = 1.0f - fabsf(fx) - fabsf(fy);
    const float t = fmaxf(-z, 0.0f);
    const float xx = fx - copysignf(t, fx);
    const float yy = fy - copysignf(t, fy);
    x = xx; y = yy;
    inv = rsqrtf(xx * xx + yy * yy + z * z);   // argument > 0 for all inputs
}

// K1: fnorm row f (16B): {oct16(n0), oct16(n1), oct16(n2), pad} — written via
// two 8B agent-scope relaxed atomics (write-through; no dirty XCD-L2 lines).
__global__ __launch_bounds__(256) void build_fnorm_kernel(
    const float*  __restrict__ vnorm,
    const int*    __restrict__ faces,
    unsigned int* __restrict__ fnorm)   // [F][4] u32
{
    const int f = blockIdx.x * blockDim.x + threadIdx.x;
    if (f >= F_) return;
    // 16B read covers the 12B face row (4B overread stays in the page).
    const i32x4 fv = *reinterpret_cast<const i32x4*>(faces + 3 * (size_t)f);
    const f32x4 n0 = *reinterpret_cast<const f32x4*>(vnorm + 3 * (size_t)fv.x);
    const f32x4 n1 = *reinterpret_cast<const f32x4*>(vnorm + 3 * (size_t)fv.y);
    const f32x4 n2 = *reinterpret_cast<const f32x4*>(vnorm + 3 * (size_t)fv.z);
    const unsigned long long e0 = oct_encode(n0.x, n0.y, n0.z);
    const unsigned long long e1 = oct_encode(n1.x, n1.y, n1.z);
    const unsigned long long e2 = oct_encode(n2.x, n2.y, n2.z);
    unsigned long long* dst =
        reinterpret_cast<unsigned long long*>(fnorm + (size_t)f * 4);
    __hip_atomic_store(dst + 0, e0 | (e1 << 32), __ATOMIC_RELAXED, __HIP_MEMORY_SCOPE_AGENT);
    __hip_atomic_store(dst + 1, e2,              __ATOMIC_RELAXED, __HIP_MEMORY_SCOPE_AGENT);
}

// K2: 2 pixels/thread (t, t+P/2). Gathers issue right after ptf arrives
// (addresses are max(fidx,0) — no dependency on the exp/weight chain), then
// the streaming loads and weight VALU overlap the gather latency.
__global__ __launch_bounds__(256) void normal_shader_kernel(
    const unsigned int* __restrict__ fnorm,
    const float*        __restrict__ bary,
    const float*        __restrict__ dists,
    const float*        __restrict__ zbuf,
    const int*          __restrict__ ptf,
    float*              __restrict__ out,
    int P)
{
    const int t = blockIdx.x * blockDim.x + threadIdx.x;
    const int halfP = P >> 1;
    if (t >= halfP) return;
    const int pp[2] = {t, t + halfP};

    // ---- Phase A: ptf first — it alone determines the gather addresses ----
    i32x4 f4[2];
#pragma unroll
    for (int j = 0; j < 2; ++j)
        f4[j] = __builtin_nontemporal_load(reinterpret_cast<const i32x4*>(ptf) + pp[j]);

    // ---- Phase B: all 8 table gathers in flight (16B each, L2-resident) ----
    u32x4 row[2][4];
#pragma unroll
    for (int j = 0; j < 2; ++j) {
        const int fidx[4] = {f4[j].x, f4[j].y, f4[j].z, f4[j].w};
#pragma unroll
        for (int k = 0; k < K_; ++k) {
            const int r = (fidx[k] < 0) ? 0 : fidx[k];   // only -1 is illegal
            row[j][k] = reinterpret_cast<const u32x4*>(fnorm)[r];
        }
    }

    // ---- Phase C: streaming loads for both pixels ----
    f32x4 dv[2], zv[2], bA[2], bB[2], bC[2];
#pragma unroll
    for (int j = 0; j < 2; ++j) {
        const int p = pp[j];
        dv[j] = __builtin_nontemporal_load(reinterpret_cast<const f32x4*>(dists) + p);
        zv[j] = __builtin_nontemporal_load(reinterpret_cast<const f32x4*>(zbuf) + p);
        const f32x4* bp = reinterpret_cast<const f32x4*>(bary + (size_t)p * 12);
        bA[j] = __builtin_nontemporal_load(bp + 0);
        bB[j] = __builtin_nontemporal_load(bp + 1);
        bC[j] = __builtin_nontemporal_load(bp + 2);
    }

    // ---- Phase D: weights (overlaps gather latency) ----
    float wn[2][4], delta[2];
#pragma unroll
    for (int j = 0; j < 2; ++j) {
        const int fidx[4] = {f4[j].x, f4[j].y, f4[j].z, f4[j].w};
        const float d[4] = {dv[j].x, dv[j].y, dv[j].z, dv[j].w};
        const float z[4] = {zv[j].x, zv[j].y, zv[j].z, zv[j].w};
        float prob[4], zinv[4], zmax = EPS_;
#pragma unroll
        for (int k = 0; k < K_; ++k) {
            const bool valid = fidx[k] >= 0;
            prob[k] = valid ? 1.0f / (1.0f + __expf(d[k] * (1.0f / SIGMA_))) : 0.0f;
            zinv[k] = valid ? (ZFAR_ - z[k]) * (1.0f / (ZFAR_ - ZNEAR_)) : 0.0f;
            zmax = fmaxf(zmax, zinv[k]);
        }
        delta[j] = fmaxf(__expf((EPS_ - zmax) * (1.0f / GAMMA_)), EPS_);
#pragma unroll
        for (int k = 0; k < K_; ++k)
            wn[j][k] = prob[k] * __expf((zinv[k] - zmax) * (1.0f / GAMMA_));
    }

    // ---- Phase E: decode + blend + store ----
#pragma unroll
    for (int j = 0; j < 2; ++j) {
        const float bb[12] = {bA[j].x, bA[j].y, bA[j].z, bA[j].w,
                              bB[j].x, bB[j].y, bB[j].z, bB[j].w,
                              bC[j].x, bC[j].y, bC[j].z, bC[j].w};
        float acc0 = 0.f, acc1 = 0.f, acc2 = 0.f, wsum = 0.f;
#pragma unroll
        for (int k = 0; k < K_; ++k) {
            const float w = wn[j][k];
            wsum += w;
            float x0, y0, z0, i0, x1, y1, z1, i1, x2, y2, z2, i2;
            oct_decode_raw(row[j][k].x, x0, y0, z0, i0);
            oct_decode_raw(row[j][k].y, x1, y1, z1, i1);
            oct_decode_raw(row[j][k].z, x2, y2, z2, i2);
            // fold w * b * (1/|v|) into one scale per normal
            const float s0 = (w * bb[3 * k + 0]) * i0;
            const float s1 = (w * bb[3 * k + 1]) * i1;
            const float s2 = (w * bb[3 * k + 2]) * i2;
            acc0 += s0 * x0 + s1 * x1 + s2 * x2;
            acc1 += s0 * y0 + s1 * y1 + s2 * y2;
            acc2 += s0 * z0 + s1 * z1 + s2 * z2;
        }
        const float inv_denom = 1.0f / (wsum + delta[j]);
        const float r0 = (acc0 + delta[j]) * inv_denom;   // bg = (1,1,1)
        const float r1 = (acc1 + delta[j]) * inv_denom;
        const float r2 = (acc2 + delta[j]) * inv_denom;
        const float nrm = fmaxf(sqrtf(r0 * r0 + r1 * r1 + r2 * r2), 1e-12f);
        const float inv = 1.0f / nrm;
        __builtin_nontemporal_store(
            f32x3{r0 * inv, r1 * inv, r2 * inv},
            reinterpret_cast<f32x3*>(out + (size_t)pp[j] * 3));
    }
}

// Fallback (proven R5 structure, exact fp32 path) if ws can't hold the table.
__global__ __launch_bounds__(256) void normal_shader_fused_kernel(
    const float* __restrict__ vnorm,
    const float* __restrict__ bary,
    const float* __restrict__ dists,
    const float* __restrict__ zbuf,
    const int*   __restrict__ faces,
    const int*   __restrict__ ptf,
    float*       __restrict__ out,
    int P)
{
    const int p = blockIdx.x * blockDim.x + threadIdx.x;
    if (p >= P) return;
    const i32x4 f4 = reinterpret_cast<const i32x4*>(ptf)[p];
    const int fidx[4] = {f4.x, f4.y, f4.z, f4.w};
    const f32x4 dv = reinterpret_cast<const f32x4*>(dists)[p];
    const f32x4 zv = reinterpret_cast<const f32x4*>(zbuf)[p];
    const float d[4] = {dv.x, dv.y, dv.z, dv.w};
    const float z[4] = {zv.x, zv.y, zv.z, zv.w};
    float prob[4], zinv[4], zmax = EPS_;
#pragma unroll
    for (int k = 0; k < K_; ++k) {
        const bool valid = fidx[k] >= 0;
        prob[k] = valid ? 1.0f / (1.0f + __expf(d[k] * (1.0f / SIGMA_))) : 0.0f;
        zinv[k] = valid ? (ZFAR_ - z[k]) * (1.0f / (ZFAR_ - ZNEAR_)) : 0.0f;
        zmax = fmaxf(zmax, zinv[k]);
    }
    const float delta = fmaxf(__expf((EPS_ - zmax) * (1.0f / GAMMA_)), EPS_);
    float wn[4];
#pragma unroll
    for (int k = 0; k < K_; ++k) wn[k] = prob[k] * __expf((zinv[k] - zmax) * (1.0f / GAMMA_));
    int cl[4];
#pragma unroll
    for (int k = 0; k < K_; ++k) cl[k] = (fidx[k] < 0) ? 0 : fidx[k];
    i32x4 fv[4];
#pragma unroll
    for (int k = 0; k < K_; ++k) fv[k] = *reinterpret_cast<const i32x4*>(faces + 3 * (size_t)cl[k]);
    const f32x4* bp = reinterpret_cast<const f32x4*>(bary + (size_t)p * 12);
    const f32x4 bA = bp[0], bB = bp[1], bC = bp[2];
    const float bb[12] = {bA.x, bA.y, bA.z, bA.w, bB.x, bB.y, bB.z, bB.w, bC.x, bC.y, bC.z, bC.w};
    f32x4 n0[4], n1[4], n2[4];
#pragma unroll
    for (int k = 0; k < K_; ++k) {
        n0[k] = *reinterpret_cast<const f32x4*>(vnorm + 3 * (size_t)fv[k].x);
        n1[k] = *reinterpret_cast<const f32x4*>(vnorm + 3 * (size_t)fv[k].y);
        n2[k] = *reinterpret_cast<const f32x4*>(vnorm + 3 * (size_t)fv[k].z);
    }
    float acc0 = 0.f, acc1 = 0.f, acc2 = 0.f, wsum = 0.f;
#pragma unroll
    for (int k = 0; k < K_; ++k) {
        wsum += wn[k];
        const float b0 = bb[3 * k], b1 = bb[3 * k + 1], b2 = bb[3 * k + 2];
        acc0 += wn[k] * (b0 * n0[k].x + b1 * n1[k].x + b2 * n2[k].x);
        acc1 += wn[k] * (b0 * n0[k].y + b1 * n1[k].y + b2 * n2[k].y);
        acc2 += wn[k] * (b0 * n0[k].z + b1 * n1[k].z + b2 * n2[k].z);
    }
    const float inv_denom = 1.0f / (wsum + delta);
    const float r0 = (acc0 + delta) * inv_denom;
    const float r1 = (acc1 + delta) * inv_denom;
    const float r2 = (acc2 + delta) * inv_denom;
    const float nrm = fmaxf(sqrtf(r0 * r0 + r1 * r1 + r2 * r2), 1e-12f);
    const float inv = 1.0f / nrm;
    float* op = out + (size_t)p * 3;
    op[0] = r0 * inv; op[1] = r1 * inv; op[2] = r2 * inv;
}

extern "C" void kernel_launch(void* const* d_in, const int* in_sizes, int n_in,
                              void* d_out, int out_size, void* d_ws, size_t ws_size,
                              hipStream_t stream) {
    // setup_inputs order: verts(0, unused), vertex_normals(1), bary_coords(2),
    // dists(3), zbuf(4), faces(5), pix_to_face(6)
    const float* vnorm = (const float*)d_in[1];
    const float* bary  = (const float*)d_in[2];
    const float* dists = (const float*)d_in[3];
    const float* zbuf  = (const float*)d_in[4];
    const int*   faces = (const int*)d_in[5];
    const int*   ptf   = (const int*)d_in[6];
    float*       out   = (float*)d_out;

    const int P = N_ * H_ * W_;
    const size_t table_bytes = (size_t)F_ * 16;  // 3.2 MB (16B oct rows)

    if (ws_size >= table_bytes) {
        unsigned int* fnorm = (unsigned int*)d_ws;
        hipLaunchKernelGGL(build_fnorm_kernel,
                           dim3((F_ + 255) / 256), dim3(256), 0, stream,
                           vnorm, faces, fnorm);
        hipLaunchKernelGGL(normal_shader_kernel,
                           dim3(((P >> 1) + 255) / 256), dim3(256), 0, stream,
                           fnorm, bary, dists, zbuf, ptf, out, P);
    } else {
        hipLaunchKernelGGL(normal_shader_fused_kernel,
                           dim3((P + 255) / 256), dim3(256), 0, stream,
                           vnorm, bary, dists, zbuf, faces, ptf, out, P);
    }
}

// Round 2
// 163.939 us; speedup vs baseline: 1.0209x; 1.0209x over previous
//
#include <hip/hip_runtime.h>
#include <hip/hip_bf16.h>

namespace {
constexpr int N_ = 4, H_ = 512, W_ = 512, K_ = 4;
constexpr int F_ = 200000;
constexpr float SIGMA_ = 1e-4f;
constexpr float GAMMA_ = 1e-4f;
constexpr float EPS_   = 1e-10f;
constexpr float ZNEAR_ = 1.0f, ZFAR_ = 100.0f;

typedef float        f32x4 __attribute__((ext_vector_type(4), aligned(4)));
typedef int          i32x4 __attribute__((ext_vector_type(4), aligned(4)));
typedef float        f32x3 __attribute__((ext_vector_type(3), aligned(4)));
typedef unsigned int u32x4 __attribute__((ext_vector_type(4), aligned(16)));
} // namespace

// R12 post-mortem of R11: putting ptf first + gathers immediately after
// DESTROYED memory-level parallelism — the wave hit the ptf s_waitcnt before
// issuing dists/zbuf/bary, serializing two HBM round-trips (shader 41->48us,
// hbm 22% of peak, VALUBusy 23%). Fix: restore R0's phase order (ALL 12
// streaming loads issued first, back to back), THEN compute gather addresses
// from ptf only (max(fidx,0) — safe: every 16B table row decodes to a finite
// vector, w==0 kills dead slots exactly) and issue the 8 gathers while the
// streaming loads are still in flight. Weight exp-chain overlaps gather
// latency. Keeps the folded w*b*rsqrt blend scale from R11.

__device__ __forceinline__ unsigned int oct_encode(float x, float y, float z) {
    const float inv = 1.0f / (fabsf(x) + fabsf(y) + fabsf(z)); // unit input
    const float px = x * inv, py = y * inv, pz = z * inv;
    // Standard octahedral wrap for the z<0 hemisphere: (1-|p.yx|)*sign(p.xy)
    const float wx = (1.0f - fabsf(py)) * copysignf(1.0f, px);
    const float wy = (1.0f - fabsf(px)) * copysignf(1.0f, py);
    const bool neg = pz < 0.0f;
    const float ex = neg ? wx : px;
    const float ey = neg ? wy : py;
    const int ix = (int)rintf(ex * 32767.0f);
    const int iy = (int)rintf(ey * 32767.0f);
    return ((unsigned int)ix & 0xffffu) | (((unsigned int)iy & 0xffffu) << 16);
}

// Raw decode: unnormalized vector + reciprocal norm (normalization folded
// into the blend scale by the caller).
__device__ __forceinline__ void oct_decode_raw(unsigned int e,
                                               float& x, float& y, float& z,
                                               float& inv) {
    const float fx = (float)(short)(unsigned short)(e & 0xffffu) * (1.0f / 32767.0f);
    const float fy = (float)(short)(unsigned short)(e >> 16)     * (1.0f / 32767.0f);
    z = 1.0f - fabsf(fx) - fabsf(fy);
    const float t = fmaxf(-z, 0.0f);
    const float xx = fx - copysignf(t, fx);
    const float yy = fy - copysignf(t, fy);
    x = xx; y = yy;
    inv = rsqrtf(xx * xx + yy * yy + z * z);   // argument > 0 for all inputs
}

// K1: fnorm row f (16B): {oct16(n0), oct16(n1), oct16(n2), pad} — written via
// two 8B agent-scope relaxed atomics (write-through; no dirty XCD-L2 lines).
__global__ __launch_bounds__(256) void build_fnorm_kernel(
    const float*  __restrict__ vnorm,
    const int*    __restrict__ faces,
    unsigned int* __restrict__ fnorm)   // [F][4] u32
{
    const int f = blockIdx.x * blockDim.x + threadIdx.x;
    if (f >= F_) return;
    // 16B read covers the 12B face row (4B overread stays in the page).
    const i32x4 fv = *reinterpret_cast<const i32x4*>(faces + 3 * (size_t)f);
    const f32x4 n0 = *reinterpret_cast<const f32x4*>(vnorm + 3 * (size_t)fv.x);
    const f32x4 n1 = *reinterpret_cast<const f32x4*>(vnorm + 3 * (size_t)fv.y);
    const f32x4 n2 = *reinterpret_cast<const f32x4*>(vnorm + 3 * (size_t)fv.z);
    const unsigned long long e0 = oct_encode(n0.x, n0.y, n0.z);
    const unsigned long long e1 = oct_encode(n1.x, n1.y, n1.z);
    const unsigned long long e2 = oct_encode(n2.x, n2.y, n2.z);
    unsigned long long* dst =
        reinterpret_cast<unsigned long long*>(fnorm + (size_t)f * 4);
    __hip_atomic_store(dst + 0, e0 | (e1 << 32), __ATOMIC_RELAXED, __HIP_MEMORY_SCOPE_AGENT);
    __hip_atomic_store(dst + 1, e2,              __ATOMIC_RELAXED, __HIP_MEMORY_SCOPE_AGENT);
}

// K2: 2 pixels/thread (t, t+P/2). Order: (A) ALL streaming loads in flight,
// (B) gathers (address = max(fidx,0), waits only on ptf = oldest load),
// (C) weight exp-chain overlapping gather latency, (D) decode+blend+store.
__global__ __launch_bounds__(256) void normal_shader_kernel(
    const unsigned int* __restrict__ fnorm,
    const float*        __restrict__ bary,
    const float*        __restrict__ dists,
    const float*        __restrict__ zbuf,
    const int*          __restrict__ ptf,
    float*              __restrict__ out,
    int P)
{
    const int t = blockIdx.x * blockDim.x + threadIdx.x;
    const int halfP = P >> 1;
    if (t >= halfP) return;
    const int pp[2] = {t, t + halfP};

    // ---- Phase A: all streaming loads for both pixels (independent) ----
    i32x4 f4[2]; f32x4 dv[2], zv[2], bA[2], bB[2], bC[2];
#pragma unroll
    for (int j = 0; j < 2; ++j) {
        const int p = pp[j];
        f4[j] = __builtin_nontemporal_load(reinterpret_cast<const i32x4*>(ptf) + p);
        dv[j] = __builtin_nontemporal_load(reinterpret_cast<const f32x4*>(dists) + p);
        zv[j] = __builtin_nontemporal_load(reinterpret_cast<const f32x4*>(zbuf) + p);
        const f32x4* bp = reinterpret_cast<const f32x4*>(bary + (size_t)p * 12);
        bA[j] = __builtin_nontemporal_load(bp + 0);
        bB[j] = __builtin_nontemporal_load(bp + 1);
        bC[j] = __builtin_nontemporal_load(bp + 2);
    }

    // ---- Phase B: 8 table gathers; address depends on ptf ONLY ----
    u32x4 row[2][4];
#pragma unroll
    for (int j = 0; j < 2; ++j) {
        const int fidx[4] = {f4[j].x, f4[j].y, f4[j].z, f4[j].w};
#pragma unroll
        for (int k = 0; k < K_; ++k) {
            const int r = (fidx[k] < 0) ? 0 : fidx[k];   // only -1 is illegal
            row[j][k] = reinterpret_cast<const u32x4*>(fnorm)[r];
        }
    }

    // ---- Phase C: weights (overlaps gather latency) ----
    float wn[2][4], delta[2];
#pragma unroll
    for (int j = 0; j < 2; ++j) {
        const int fidx[4] = {f4[j].x, f4[j].y, f4[j].z, f4[j].w};
        const float d[4] = {dv[j].x, dv[j].y, dv[j].z, dv[j].w};
        const float z[4] = {zv[j].x, zv[j].y, zv[j].z, zv[j].w};
        float prob[4], zinv[4], zmax = EPS_;
#pragma unroll
        for (int k = 0; k < K_; ++k) {
            const bool valid = fidx[k] >= 0;
            prob[k] = valid ? 1.0f / (1.0f + __expf(d[k] * (1.0f / SIGMA_))) : 0.0f;
            zinv[k] = valid ? (ZFAR_ - z[k]) * (1.0f / (ZFAR_ - ZNEAR_)) : 0.0f;
            zmax = fmaxf(zmax, zinv[k]);
        }
        delta[j] = fmaxf(__expf((EPS_ - zmax) * (1.0f / GAMMA_)), EPS_);
#pragma unroll
        for (int k = 0; k < K_; ++k)
            wn[j][k] = prob[k] * __expf((zinv[k] - zmax) * (1.0f / GAMMA_));
    }

    // ---- Phase D: decode + blend + store ----
#pragma unroll
    for (int j = 0; j < 2; ++j) {
        const float bb[12] = {bA[j].x, bA[j].y, bA[j].z, bA[j].w,
                              bB[j].x, bB[j].y, bB[j].z, bB[j].w,
                              bC[j].x, bC[j].y, bC[j].z, bC[j].w};
        float acc0 = 0.f, acc1 = 0.f, acc2 = 0.f, wsum = 0.f;
#pragma unroll
        for (int k = 0; k < K_; ++k) {
            const float w = wn[j][k];
            wsum += w;
            float x0, y0, z0, i0, x1, y1, z1, i1, x2, y2, z2, i2;
            oct_decode_raw(row[j][k].x, x0, y0, z0, i0);
            oct_decode_raw(row[j][k].y, x1, y1, z1, i1);
            oct_decode_raw(row[j][k].z, x2, y2, z2, i2);
            // fold w * b * (1/|v|) into one scale per normal
            const float s0 = (w * bb[3 * k + 0]) * i0;
            const float s1 = (w * bb[3 * k + 1]) * i1;
            const float s2 = (w * bb[3 * k + 2]) * i2;
            acc0 += s0 * x0 + s1 * x1 + s2 * x2;
            acc1 += s0 * y0 + s1 * y1 + s2 * y2;
            acc2 += s0 * z0 + s1 * z1 + s2 * z2;
        }
        const float inv_denom = 1.0f / (wsum + delta[j]);
        const float r0 = (acc0 + delta[j]) * inv_denom;   // bg = (1,1,1)
        const float r1 = (acc1 + delta[j]) * inv_denom;
        const float r2 = (acc2 + delta[j]) * inv_denom;
        const float nrm = fmaxf(sqrtf(r0 * r0 + r1 * r1 + r2 * r2), 1e-12f);
        const float inv = 1.0f / nrm;
        __builtin_nontemporal_store(
            f32x3{r0 * inv, r1 * inv, r2 * inv},
            reinterpret_cast<f32x3*>(out + (size_t)pp[j] * 3));
    }
}

// Fallback (proven R5 structure, exact fp32 path) if ws can't hold the table.
__global__ __launch_bounds__(256) void normal_shader_fused_kernel(
    const float* __restrict__ vnorm,
    const float* __restrict__ bary,
    const float* __restrict__ dists,
    const float* __restrict__ zbuf,
    const int*   __restrict__ faces,
    const int*   __restrict__ ptf,
    float*       __restrict__ out,
    int P)
{
    const int p = blockIdx.x * blockDim.x + threadIdx.x;
    if (p >= P) return;
    const i32x4 f4 = reinterpret_cast<const i32x4*>(ptf)[p];
    const int fidx[4] = {f4.x, f4.y, f4.z, f4.w};
    const f32x4 dv = reinterpret_cast<const f32x4*>(dists)[p];
    const f32x4 zv = reinterpret_cast<const f32x4*>(zbuf)[p];
    const float d[4] = {dv.x, dv.y, dv.z, dv.w};
    const float z[4] = {zv.x, zv.y, zv.z, zv.w};
    float prob[4], zinv[4], zmax = EPS_;
#pragma unroll
    for (int k = 0; k < K_; ++k) {
        const bool valid = fidx[k] >= 0;
        prob[k] = valid ? 1.0f / (1.0f + __expf(d[k] * (1.0f / SIGMA_))) : 0.0f;
        zinv[k] = valid ? (ZFAR_ - z[k]) * (1.0f / (ZFAR_ - ZNEAR_)) : 0.0f;
        zmax = fmaxf(zmax, zinv[k]);
    }
    const float delta = fmaxf(__expf((EPS_ - zmax) * (1.0f / GAMMA_)), EPS_);
    float wn[4];
#pragma unroll
    for (int k = 0; k < K_; ++k) wn[k] = prob[k] * __expf((zinv[k] - zmax) * (1.0f / GAMMA_));
    int cl[4];
#pragma unroll
    for (int k = 0; k < K_; ++k) cl[k] = (fidx[k] < 0) ? 0 : fidx[k];
    i32x4 fv[4];
#pragma unroll
    for (int k = 0; k < K_; ++k) fv[k] = *reinterpret_cast<const i32x4*>(faces + 3 * (size_t)cl[k]);
    const f32x4* bp = reinterpret_cast<const f32x4*>(bary + (size_t)p * 12);
    const f32x4 bA = bp[0], bB = bp[1], bC = bp[2];
    const float bb[12] = {bA.x, bA.y, bA.z, bA.w, bB.x, bB.y, bB.z, bB.w, bC.x, bC.y, bC.z, bC.w};
    f32x4 n0[4], n1[4], n2[4];
#pragma unroll
    for (int k = 0; k < K_; ++k) {
        n0[k] = *reinterpret_cast<const f32x4*>(vnorm + 3 * (size_t)fv[k].x);
        n1[k] = *reinterpret_cast<const f32x4*>(vnorm + 3 * (size_t)fv[k].y);
        n2[k] = *reinterpret_cast<const f32x4*>(vnorm + 3 * (size_t)fv[k].z);
    }
    float acc0 = 0.f, acc1 = 0.f, acc2 = 0.f, wsum = 0.f;
#pragma unroll
    for (int k = 0; k < K_; ++k) {
        wsum += wn[k];
        const float b0 = bb[3 * k], b1 = bb[3 * k + 1], b2 = bb[3 * k + 2];
        acc0 += wn[k] * (b0 * n0[k].x + b1 * n1[k].x + b2 * n2[k].x);
        acc1 += wn[k] * (b0 * n0[k].y + b1 * n1[k].y + b2 * n2[k].y);
        acc2 += wn[k] * (b0 * n0[k].z + b1 * n1[k].z + b2 * n2[k].z);
    }
    const float inv_denom = 1.0f / (wsum + delta);
    const float r0 = (acc0 + delta) * inv_denom;
    const float r1 = (acc1 + delta) * inv_denom;
    const float r2 = (acc2 + delta) * inv_denom;
    const float nrm = fmaxf(sqrtf(r0 * r0 + r1 * r1 + r2 * r2), 1e-12f);
    const float inv = 1.0f / nrm;
    float* op = out + (size_t)p * 3;
    op[0] = r0 * inv; op[1] = r1 * inv; op[2] = r2 * inv;
}

extern "C" void kernel_launch(void* const* d_in, const int* in_sizes, int n_in,
                              void* d_out, int out_size, void* d_ws, size_t ws_size,
                              hipStream_t stream) {
    // setup_inputs order: verts(0, unused), vertex_normals(1), bary_coords(2),
    // dists(3), zbuf(4), faces(5), pix_to_face(6)
    const float* vnorm = (const float*)d_in[1];
    const float* bary  = (const float*)d_in[2];
    const float* dists = (const float*)d_in[3];
    const float* zbuf  = (const float*)d_in[4];
    const int*   faces = (const int*)d_in[5];
    const int*   ptf   = (const int*)d_in[6];
    float*       out   = (float*)d_out;

    const int P = N_ * H_ * W_;
    const size_t table_bytes = (size_t)F_ * 16;  // 3.2 MB (16B oct rows)

    if (ws_size >= table_bytes) {
        unsigned int* fnorm = (unsigned int*)d_ws;
        hipLaunchKernelGGL(build_fnorm_kernel,
                           dim3((F_ + 255) / 256), dim3(256), 0, stream,
                           vnorm, faces, fnorm);
        hipLaunchKernelGGL(normal_shader_kernel,
                           dim3(((P >> 1) + 255) / 256), dim3(256), 0, stream,
                           fnorm, bary, dists, zbuf, ptf, out, P);
    } else {
        hipLaunchKernelGGL(normal_shader_fused_kernel,
                           dim3((P + 255) / 256), dim3(256), 0, stream,
                           vnorm, bary, dists, zbuf, faces, ptf, out, P);
    }
}